// Round 5
// baseline (250.055 us; speedup 1.0000x reference)
//
#include <hip/hip_runtime.h>
#include <math.h>

#define H 1024
#define S 32768
#define NPART 16          // d-partials for the W^T @ hidden matvec
#define RPW 8             // rows per wave in K2
#define NB2 1024          // K2 blocks: S / (4 waves * RPW)
#define NWORK 8           // tail finalize worker blocks

// ws layout (floats):
//   [0, 16384)        part[p][h]   p<16, h<1024
//   [16384, 17408)    pm[NB2]      per-block softmax max
//   [17408, 18432)    ps[NB2]      per-block softmax sumexp
//   [18432, 51200)    scores[S]
//   [51200]           ctr (int)    finish-ticket counter (zeroed by K1)
#define WS_PART   0
#define WS_PM     16384
#define WS_PS     17408
#define WS_SCORES 18432
#define WS_CTR    51200

// ---------------------------------------------------------------------------
// K1: part[by][h] = sum_{d in by-chunk of 64} W[d][h] * hidden[d]
// grid (16,16), block 256. Also zeroes the ticket counter for K2 (stream
// order makes it visible before K2 starts -- no extra memset dispatch).
// ---------------------------------------------------------------------------
__global__ __launch_bounds__(256) void matvec_partial(const float* __restrict__ W,
                                                      const float* __restrict__ hidden,
                                                      float* __restrict__ ws) {
    float* part = ws + WS_PART;
    if (blockIdx.x == 0 && blockIdx.y == 0 && threadIdx.x == 0)
        *(int*)(ws + WS_CTR) = 0;

    const int t  = threadIdx.x;
    const int l  = t & 63;
    const int dg = t >> 6;
    const int h  = blockIdx.x * 64 + l;
    const int d0 = blockIdx.y * 64 + dg * 16;

    float acc = 0.f;
#pragma unroll
    for (int i = 0; i < 16; ++i)
        acc += W[(size_t)(d0 + i) * H + h] * hidden[d0 + i];

    __shared__ float red[4][64];
    red[dg][l] = acc;
    __syncthreads();
    if (t < 64)
        part[blockIdx.y * H + blockIdx.x * 64 + l] =
            red[0][l] + red[1][l] + red[2][l] + red[3][l];
}

// ---------------------------------------------------------------------------
// K2: v-rebuild prologue + scores + per-block softmax partials + ticket-based
// tail finalize. 1024 blocks x 256 threads. The last NWORK blocks to finish
// (by atomic ticket) each normalize 1/NWORK of the outputs; micro-spin only
// for <=7 stragglers, at end-of-kernel, AFTER all HBM streaming is done
// (unlike R2's mid-stream global spin, which was catastrophic).
// ---------------------------------------------------------------------------
__device__ __forceinline__ float4 add4(float4 a, float4 b) {
    return make_float4(a.x + b.x, a.y + b.y, a.z + b.z, a.w + b.w);
}

__device__ __forceinline__ float dot16(const float4 e0, const float4 e1,
                                       const float4 e2, const float4 e3,
                                       const float4 vf[4]) {
    float s0 = e0.x * vf[0].x + e0.y * vf[0].y + e0.z * vf[0].z + e0.w * vf[0].w;
    float s1 = e1.x * vf[1].x + e1.y * vf[1].y + e1.z * vf[1].z + e1.w * vf[1].w;
    float s2 = e2.x * vf[2].x + e2.y * vf[2].y + e2.z * vf[2].z + e2.w * vf[2].w;
    float s3 = e3.x * vf[3].x + e3.y * vf[3].y + e3.z * vf[3].z + e3.w * vf[3].w;
    return (s0 + s1) + (s2 + s3);
}

__global__ __launch_bounds__(256) void scores_partial(const float* __restrict__ enc,
                                                      float* __restrict__ ws,
                                                      float* __restrict__ out) {
    float* scores = ws + WS_SCORES;
    float* pm     = ws + WS_PM;
    float* ps     = ws + WS_PS;
    const float* part = ws + WS_PART;
    int* ctr = (int*)(ws + WS_CTR);

    const int tid  = threadIdx.x;
    const int lane = tid & 63;
    const int wv   = tid >> 6;
    const int blk  = blockIdx.x;
    const int gw   = blk * 4 + wv;                 // global wave id
    const size_t row0 = (size_t)gw * RPW;

    // --- prefetch first 2 enc rows: HBM stream starts before the prologue ---
    const float4* e4 = (const float4*)(enc + row0 * H);
    float4 p00 = e4[lane],       p01 = e4[lane + 64],
           p02 = e4[lane + 128], p03 = e4[lane + 192];
    float4 p10 = e4[256 + lane],       p11 = e4[256 + lane + 64],
           p12 = e4[256 + lane + 128], p13 = e4[256 + lane + 192];

    // --- v-rebuild prologue: 16 independent L2 loads, tree sum, LDS ---
    __shared__ float vsh[H];
    {
        const float4* p4 = (const float4*)part;
        float4 t[NPART];
#pragma unroll
        for (int p = 0; p < NPART; ++p) t[p] = p4[p * (H / 4) + tid];
#pragma unroll
        for (int p = 0; p < 8; ++p) t[p] = add4(t[p], t[p + 8]);
#pragma unroll
        for (int p = 0; p < 4; ++p) t[p] = add4(t[p], t[p + 4]);
        ((float4*)vsh)[tid] = add4(add4(t[0], t[2]), add4(t[1], t[3]));
    }
    __syncthreads();

    const float4* v4 = (const float4*)vsh;
    float4 vf[4];
#pragma unroll
    for (int k = 0; k < 4; ++k) vf[k] = v4[lane + 64 * k];

    float a[RPW];
    a[0] = dot16(p00, p01, p02, p03, vf);
    a[1] = dot16(p10, p11, p12, p13, vf);
#pragma unroll
    for (int it = 2; it < RPW; ++it) {
        const float4* r = e4 + it * 256;
        a[it] = dot16(r[lane], r[lane + 64], r[lane + 128], r[lane + 192], vf);
    }

    // butterfly each row; full row-sum lands in ALL lanes
#pragma unroll
    for (int it = 0; it < RPW; ++it) {
#pragma unroll
        for (int off = 32; off > 0; off >>= 1)
            a[it] += __shfl_xor(a[it], off, 64);
    }
    if (lane == 0) {
        *(float4*)(scores + row0)     = make_float4(a[0], a[1], a[2], a[3]);
        *(float4*)(scores + row0 + 4) = make_float4(a[4], a[5], a[6], a[7]);
    }

    // deferred wave softmax partial: fmax tree + independent exps
    float m01 = fmaxf(a[0], a[1]), m23 = fmaxf(a[2], a[3]);
    float m45 = fmaxf(a[4], a[5]), m67 = fmaxf(a[6], a[7]);
    const float mw = fmaxf(fmaxf(m01, m23), fmaxf(m45, m67));
    float sw = 0.f;
#pragma unroll
    for (int it = 0; it < RPW; ++it) sw += __expf(a[it] - mw);

    __shared__ float sm[4], ss[4];
    if (lane == 0) { sm[wv] = mw; ss[wv] = sw; }
    __syncthreads();
    if (tid == 0) {
        float m = sm[0], s = ss[0];
#pragma unroll
        for (int i = 1; i < 4; ++i) {
            const float nm = fmaxf(m, sm[i]);
            s = s * __expf(m - nm) + ss[i] * __expf(sm[i] - nm);
            m = nm;
        }
        pm[blk] = m; ps[blk] = s;
    }

    // ---- ticket: one release-atomic per block, AFTER all stores drained ----
    __shared__ int ticket_sh;
    __syncthreads();                 // drains vmcnt: scores + pm/ps issued
    if (tid == 0)
        ticket_sh = __hip_atomic_fetch_add(ctr, 1, __ATOMIC_RELEASE,
                                           __HIP_MEMORY_SCOPE_AGENT);
    __syncthreads();
    const int ticket = ticket_sh;
    if (ticket < NB2 - NWORK) return;            // non-workers exit

    // ---- tail worker: slice w of the finalize ----
    const int w = ticket - (NB2 - NWORK);        // 0..NWORK-1, unique

    if (tid == 0) {                              // micro-spin for <=7 stragglers
        int guard = 0;
        while (__hip_atomic_load(ctr, __ATOMIC_RELAXED,
                                 __HIP_MEMORY_SCOPE_AGENT) < NB2) {
            __builtin_amdgcn_s_sleep(1);
            if (++guard > 100000000) break;      // fail loud, never hang
        }
    }
    __syncthreads();
    __threadfence();                             // acquire: see all scores/pm/ps

    // combine all 1024 (m,s) pairs (identical order/math to the old K3)
    float m = -INFINITY, s = 0.f;
#pragma unroll
    for (int i = 0; i < NB2 / 256; ++i) {
        const int idx = tid + i * 256;
        const float om = pm[idx], os = ps[idx];
        const float nm = fmaxf(m, om);
        s = s * __expf(m - nm) + os * __expf(om - nm);
        m = nm;
    }
#pragma unroll
    for (int off = 32; off > 0; off >>= 1) {
        const float om = __shfl_xor(m, off, 64);
        const float os = __shfl_xor(s, off, 64);
        const float nm = fmaxf(m, om);
        s = s * __expf(m - nm) + os * __expf(om - nm);
        m = nm;
    }
    __syncthreads();                             // sm/ss reuse
    if (lane == 0) { sm[wv] = m; ss[wv] = s; }
    __syncthreads();
    float M = sm[0], Ssum = ss[0];
#pragma unroll
    for (int i = 1; i < 4; ++i) {
        const float nm = fmaxf(M, sm[i]);
        Ssum = Ssum * __expf(M - nm) + ss[i] * __expf(sm[i] - nm);
        M = nm;
    }
    const float rs = 1.0f / Ssum;

    // normalize slice w: 4096 outputs, float4-coalesced
    const float4* sc4 = (const float4*)scores + w * 1024;
    float4* out4      = (float4*)out + w * 1024;
#pragma unroll
    for (int j = 0; j < 4; ++j) {
        const float4 sv = sc4[j * 256 + tid];
        out4[j * 256 + tid] = make_float4(__expf(sv.x - M) * rs,
                                          __expf(sv.y - M) * rs,
                                          __expf(sv.z - M) * rs,
                                          __expf(sv.w - M) * rs);
    }
}

extern "C" void kernel_launch(void* const* d_in, const int* in_sizes, int n_in,
                              void* d_out, int out_size, void* d_ws, size_t ws_size,
                              hipStream_t stream) {
    const float* hidden = (const float*)d_in[0];   // [H]
    const float* enc    = (const float*)d_in[1];   // [S, H]
    const float* W      = (const float*)d_in[2];   // [H, H]
    // d_in[3] = b — unused: b·hidden is a uniform softmax shift (cancels exactly).
    float* out = (float*)d_out;                    // [S] fp32
    float* ws  = (float*)d_ws;

    matvec_partial<<<dim3(16, 16), 256, 0, stream>>>(W, hidden, ws);
    scores_partial<<<NB2, 256, 0, stream>>>(enc, ws, out);
}

// Round 6
// 200.353 us; speedup vs baseline: 1.2481x; 1.2481x over previous
//
#include <hip/hip_runtime.h>
#include <math.h>

#define H 1024
#define S 32768
#define NPART 16          // d-partials for the W^T @ hidden matvec
#define RPW 4             // rows per wave in K2
#define NB2 2048          // K2 blocks: S / (4 waves * RPW)

// ws layout (floats):
//   [0, 16384)        part[p][h]   p<16, h<1024
//   [16384, 18432)    pm[NB2]      per-block softmax max
//   [18432, 20480)    ps[NB2]      per-block softmax sumexp
//   [20480, 53248)    scores[S]
#define WS_PART   0
#define WS_PM     16384
#define WS_PS     18432
#define WS_SCORES 20480

// ---------------------------------------------------------------------------
// K1: part[by][h] = sum_{d in by-chunk of 64} W[d][h] * hidden[d]
// grid (16,16), block 256. One block per CU, coalesced W reads.
// ---------------------------------------------------------------------------
__global__ __launch_bounds__(256) void matvec_partial(const float* __restrict__ W,
                                                      const float* __restrict__ hidden,
                                                      float* __restrict__ ws) {
    float* part = ws + WS_PART;
    const int t  = threadIdx.x;
    const int l  = t & 63;
    const int dg = t >> 6;
    const int h  = blockIdx.x * 64 + l;
    const int d0 = blockIdx.y * 64 + dg * 16;

    float acc = 0.f;
#pragma unroll
    for (int i = 0; i < 16; ++i)
        acc += W[(size_t)(d0 + i) * H + h] * hidden[d0 + i];

    __shared__ float red[4][64];
    red[dg][l] = acc;
    __syncthreads();
    if (t < 64)
        part[blockIdx.y * H + blockIdx.x * 64 + l] =
            red[0][l] + red[1][l] + red[2][l] + red[3][l];
}

// ---------------------------------------------------------------------------
// K2: v-rebuild prologue + scores + per-block softmax partials.
// 2048 blocks x 256 threads, RPW=4 rows/wave.
// KEY CHANGE (R5 diagnosis: VGPR=56 -> only ~4 loads in flight -> 2.7 TB/s,
// latency-bound): all 16 row-loads are issued into an explicit register
// array BEFORE any dot, and __launch_bounds__(256,4) grants the VGPR budget
// (~100) so the compiler keeps them in flight. Target ~5 KB/CU outstanding.
// ---------------------------------------------------------------------------
__device__ __forceinline__ float4 add4(float4 a, float4 b) {
    return make_float4(a.x + b.x, a.y + b.y, a.z + b.z, a.w + b.w);
}

__global__ __launch_bounds__(256, 4) void scores_partial(const float* __restrict__ enc,
                                                         float* __restrict__ ws) {
    float* scores = ws + WS_SCORES;
    float* pm     = ws + WS_PM;
    float* ps     = ws + WS_PS;
    const float* part = ws + WS_PART;

    const int tid  = threadIdx.x;
    const int lane = tid & 63;
    const int wv   = tid >> 6;
    const int blk  = blockIdx.x;
    const int gw   = blk * 4 + wv;                 // global wave id
    const size_t row0 = (size_t)gw * RPW;

    // --- v-rebuild prologue: 16 independent L2 loads, tree sum, LDS ---
    __shared__ float vsh[H];
    {
        const float4* p4 = (const float4*)part;
        float4 t[NPART];
#pragma unroll
        for (int p = 0; p < NPART; ++p) t[p] = p4[p * (H / 4) + tid];
#pragma unroll
        for (int p = 0; p < 8; ++p) t[p] = add4(t[p], t[p + 8]);
#pragma unroll
        for (int p = 0; p < 4; ++p) t[p] = add4(t[p], t[p + 4]);
        ((float4*)vsh)[tid] = add4(add4(t[0], t[2]), add4(t[1], t[3]));
    }
    __syncthreads();

    // --- issue ALL 16 enc loads up front (4 rows x 4 float4/lane) ---
    const float4* e4 = (const float4*)(enc + row0 * H);
    float4 r[16];
#pragma unroll
    for (int it = 0; it < RPW; ++it)
#pragma unroll
        for (int k = 0; k < 4; ++k)
            r[it * 4 + k] = e4[it * 256 + k * 64 + lane];

    // --- v fragments from LDS (lgkm path; overlaps with vmem waits) ---
    const float4* v4 = (const float4*)vsh;
    float4 vf[4];
#pragma unroll
    for (int k = 0; k < 4; ++k) vf[k] = v4[lane + 64 * k];

    // --- dots: compiler waits vmcnt progressively as rows arrive ---
    float a[RPW];
#pragma unroll
    for (int it = 0; it < RPW; ++it) {
        const float4 e0 = r[it * 4 + 0], e1 = r[it * 4 + 1];
        const float4 e2 = r[it * 4 + 2], e3 = r[it * 4 + 3];
        float s0 = e0.x * vf[0].x + e0.y * vf[0].y + e0.z * vf[0].z + e0.w * vf[0].w;
        float s1 = e1.x * vf[1].x + e1.y * vf[1].y + e1.z * vf[1].z + e1.w * vf[1].w;
        float s2 = e2.x * vf[2].x + e2.y * vf[2].y + e2.z * vf[2].z + e2.w * vf[2].w;
        float s3 = e3.x * vf[3].x + e3.y * vf[3].y + e3.z * vf[3].z + e3.w * vf[3].w;
        a[it] = (s0 + s1) + (s2 + s3);
    }

    // butterfly each row; full row-sum lands in ALL lanes
#pragma unroll
    for (int it = 0; it < RPW; ++it) {
#pragma unroll
        for (int off = 32; off > 0; off >>= 1)
            a[it] += __shfl_xor(a[it], off, 64);
    }
    if (lane == 0)
        *(float4*)(scores + row0) = make_float4(a[0], a[1], a[2], a[3]);

    // deferred wave softmax partial (exact R3 ordering)
    const float mw = fmaxf(fmaxf(a[0], a[1]), fmaxf(a[2], a[3]));
    float sw = __expf(a[0] - mw) + __expf(a[1] - mw) +
               __expf(a[2] - mw) + __expf(a[3] - mw);

    __shared__ float sm[4], ss[4];
    if (lane == 0) { sm[wv] = mw; ss[wv] = sw; }
    __syncthreads();
    if (tid == 0) {
        float m = sm[0], s = ss[0];
#pragma unroll
        for (int i = 1; i < 4; ++i) {
            const float nm = fmaxf(m, sm[i]);
            s = s * __expf(m - nm) + ss[i] * __expf(sm[i] - nm);
            m = nm;
        }
        pm[blk] = m; ps[blk] = s;
    }
}

// ---------------------------------------------------------------------------
// K3: every block redundantly combines the 2048 (m,s) pairs, then
// normalizes its 256 scores. grid 128 blocks x 256 threads.
// ---------------------------------------------------------------------------
__global__ __launch_bounds__(256) void finalize(const float* __restrict__ ws,
                                                float* __restrict__ out) {
    const float* scores = ws + WS_SCORES;
    const float* pm     = ws + WS_PM;
    const float* ps     = ws + WS_PS;

    const int tid  = threadIdx.x;
    const int lane = tid & 63;
    const int wv   = tid >> 6;

    float m = -INFINITY, s = 0.f;
#pragma unroll
    for (int i = 0; i < NB2 / 256; ++i) {
        const int idx = tid + i * 256;
        const float om = pm[idx], os = ps[idx];
        const float nm = fmaxf(m, om);
        s = s * __expf(m - nm) + os * __expf(om - nm);
        m = nm;
    }
#pragma unroll
    for (int off = 32; off > 0; off >>= 1) {
        const float om = __shfl_xor(m, off, 64);
        const float os = __shfl_xor(s, off, 64);
        const float nm = fmaxf(m, om);
        s = s * __expf(m - nm) + os * __expf(om - nm);
        m = nm;
    }
    __shared__ float sm[4], ss[4];
    if (lane == 0) { sm[wv] = m; ss[wv] = s; }
    __syncthreads();
    float M = sm[0], Ssum = ss[0];
#pragma unroll
    for (int i = 1; i < 4; ++i) {
        const float nm = fmaxf(M, sm[i]);
        Ssum = Ssum * __expf(M - nm) + ss[i] * __expf(sm[i] - nm);
        M = nm;
    }
    const float rs = 1.0f / Ssum;

    const int i = blockIdx.x * 256 + tid;
    out[i] = __expf(scores[i] - M) * rs;
}

extern "C" void kernel_launch(void* const* d_in, const int* in_sizes, int n_in,
                              void* d_out, int out_size, void* d_ws, size_t ws_size,
                              hipStream_t stream) {
    const float* hidden = (const float*)d_in[0];   // [H]
    const float* enc    = (const float*)d_in[1];   // [S, H]
    const float* W      = (const float*)d_in[2];   // [H, H]
    // d_in[3] = b — unused: b·hidden is a uniform softmax shift (cancels exactly).
    float* out = (float*)d_out;                    // [S] fp32
    float* ws  = (float*)d_ws;

    matvec_partial<<<dim3(16, 16), 256, 0, stream>>>(W, hidden, ws);
    scores_partial<<<NB2, 256, 0, stream>>>(enc, ws);
    finalize<<<S / 256, 256, 0, stream>>>(ws, out);
}